// Round 5
// baseline (21537.737 us; speedup 1.0000x reference)
//
#include <hip/hip_runtime.h>
#include <hip/hip_fp16.h>

#define T_LEN 2048
#define HID   2048
#define G4    8192
#define NV    128

typedef _Float16 h2_t __attribute__((ext_vector_type(2)));
typedef unsigned u32x4 __attribute__((ext_vector_type(4)));

__device__ __forceinline__ float uplo(unsigned u) {
  return __half2float(__ushort_as_half((unsigned short)(u & 0xffffu)));
}
__device__ __forceinline__ float uphi(unsigned u) {
  return __half2float(__ushort_as_half((unsigned short)(u >> 16)));
}
__device__ __forceinline__ unsigned pku(float a, float b) {
  unsigned lo = (unsigned)__half_as_ushort(__float2half_rn(a));
  unsigned hi = (unsigned)__half_as_ushort(__float2half_rn(b));
  return lo | (hi << 16);
}
__device__ __forceinline__ unsigned pkh(float h, unsigned tag) {
  return (tag << 16) | (unsigned)__half_as_ushort(__float2half_rn(h));
}
__device__ __forceinline__ h2_t pk2(float a, float bb) {
  return __builtin_bit_cast(h2_t, __builtin_amdgcn_cvt_pkrtz(a, bb));
}
__device__ __forceinline__ h2_t bc2(unsigned u) {
  return __builtin_bit_cast(h2_t, u);
}

// Dual coherent 16B loads, latencies overlapped. (uint4 OUTPUTS are fine;
// only struct INPUTS break the "v" constraint.)
__device__ __forceinline__ void ld_sc16x2(const unsigned* p0, const unsigned* p1,
                                          uint4& r0, uint4& r1) {
  asm volatile("global_load_dwordx4 %0, %2, off sc0 sc1\n\t"
               "global_load_dwordx4 %1, %3, off sc0 sc1\n\t"
               "s_waitcnt vmcnt(0)"
               : "=v"(r0), "=v"(r1) : "v"(p0), "v"(p1) : "memory");
}
// Quad coherent 16B loads (L1 group: two rows at once).
__device__ __forceinline__ void ld_sc16x4(const unsigned* p0, const unsigned* p1,
                                          const unsigned* p2, const unsigned* p3,
                                          uint4& r0, uint4& r1, uint4& r2, uint4& r3) {
  asm volatile("global_load_dwordx4 %0, %4, off sc0 sc1\n\t"
               "global_load_dwordx4 %1, %5, off sc0 sc1\n\t"
               "global_load_dwordx4 %2, %6, off sc0 sc1\n\t"
               "global_load_dwordx4 %3, %7, off sc0 sc1\n\t"
               "s_waitcnt vmcnt(0)"
               : "=v"(r0), "=v"(r1), "=v"(r2), "=v"(r3)
               : "v"(p0), "v"(p1), "v"(p2), "v"(p3) : "memory");
}
// Coherent 4B store (fire-and-forget tagged publish).
__device__ __forceinline__ void st_sc4(unsigned* p, unsigned v) {
  asm volatile("global_store_dword %0, %1, off sc0 sc1"
               :: "v"(p), "v"(v) : "memory");
}

__device__ __forceinline__ float fsigmoid(float x) {
  return __builtin_amdgcn_rcpf(1.f + __expf(-x));
}
__device__ __forceinline__ float ftanh(float x) {
  return 2.f * __builtin_amdgcn_rcpf(1.f + __expf(-2.f * x)) - 1.f;
}

// 4-wave group barrier on an LDS counter (monotone target = 4*step).
// Valve-bounded: a broken protocol degrades to wrong-answer, not a hang.
__device__ __forceinline__ void gbar(unsigned* cnt, unsigned target, int lane) {
  if (lane == 0)
    __hip_atomic_fetch_add(cnt, 1u, __ATOMIC_ACQ_REL, __HIP_MEMORY_SCOPE_WORKGROUP);
  int it = 0;
  while (__hip_atomic_load(cnt, __ATOMIC_ACQUIRE, __HIP_MEMORY_SCOPE_WORKGROUP) < target) {
    if (++it > (1 << 15)) break;
  }
}

// ---------------- GEMM: Gp[M][N/2] (packed f16 pairs) = A@B^T + (b1+b2) -------------
__global__ __launch_bounds__(256, 2) void gemm_bias_pk(
    const float* __restrict__ A, const float* __restrict__ B,
    const float* __restrict__ b1, const float* __restrict__ b2,
    unsigned* __restrict__ Gp)
{
  const int K = 2048;
  __shared__ float As[32][68];
  __shared__ float Bs[32][68];
  const int tid = threadIdx.x;
  const int tx = tid & 15, ty = tid >> 4;
  const int row0 = blockIdx.y * 64, col0 = blockIdx.x * 64;
  const int lk = (tid & 7) * 4, lr = tid >> 3;
  float acc[4][4] = {};
  for (int k0 = 0; k0 < K; k0 += 32) {
    float4 a0 = *(const float4*)&A[(size_t)(row0 + lr)      * K + k0 + lk];
    float4 a1 = *(const float4*)&A[(size_t)(row0 + lr + 32) * K + k0 + lk];
    float4 bb0 = *(const float4*)&B[(size_t)(col0 + lr)      * K + k0 + lk];
    float4 bb1 = *(const float4*)&B[(size_t)(col0 + lr + 32) * K + k0 + lk];
    __syncthreads();
    As[lk+0][lr] = a0.x;  As[lk+1][lr] = a0.y;  As[lk+2][lr] = a0.z;  As[lk+3][lr] = a0.w;
    As[lk+0][lr+32] = a1.x; As[lk+1][lr+32] = a1.y; As[lk+2][lr+32] = a1.z; As[lk+3][lr+32] = a1.w;
    Bs[lk+0][lr] = bb0.x; Bs[lk+1][lr] = bb0.y; Bs[lk+2][lr] = bb0.z; Bs[lk+3][lr] = bb0.w;
    Bs[lk+0][lr+32] = bb1.x; Bs[lk+1][lr+32] = bb1.y; Bs[lk+2][lr+32] = bb1.z; Bs[lk+3][lr+32] = bb1.w;
    __syncthreads();
    #pragma unroll
    for (int kk = 0; kk < 32; ++kk) {
      float4 av = *(const float4*)&As[kk][ty * 4];
      float4 bv = *(const float4*)&Bs[kk][tx * 4];
      float am[4] = {av.x, av.y, av.z, av.w};
      float bm[4] = {bv.x, bv.y, bv.z, bv.w};
      #pragma unroll
      for (int i = 0; i < 4; ++i)
        #pragma unroll
        for (int j = 0; j < 4; ++j)
          acc[i][j] = fmaf(am[i], bm[j], acc[i][j]);
    }
  }
  const int cc = col0 + tx * 4;
  const float bbv0 = b1[cc+0] + b2[cc+0];
  const float bbv1 = b1[cc+1] + b2[cc+1];
  const float bbv2 = b1[cc+2] + b2[cc+2];
  const float bbv3 = b1[cc+3] + b2[cc+3];
  #pragma unroll
  for (int i = 0; i < 4; ++i) {
    const int r = row0 + ty * 4 + i;
    unsigned* gp = Gp + (size_t)r * (G4 / 2) + (cc >> 1);
    gp[0] = pku(acc[i][0] + bbv0, acc[i][1] + bbv1);
    gp[1] = pku(acc[i][2] + bbv2, acc[i][3] + bbv3);
  }
}

// ---------------- Wih1 f32 -> packed f16 pairs ----------------
__global__ __launch_bounds__(256) void conv_pk(
    const float* __restrict__ in, unsigned* __restrict__ out, int nquad)
{
  for (size_t m = (size_t)blockIdx.x * 256 + threadIdx.x; m < (size_t)nquad;
       m += (size_t)gridDim.x * 256) {
    float4 f = *(const float4*)&in[4 * m];
    uint2 o;
    o.x = pku(f.x, f.y);
    o.y = pku(f.z, f.w);
    *(uint2*)&out[2 * m] = o;
  }
}

// ---------------- Fused 2-layer, wave-specialized, self-timed ----------------
// 256 WGs x 512 threads, 1 WG/CU. Waves 0-3: layer 0 (critical chain), each
// owns j = 8b+2w, 8b+2w+1. Waves 4-7: layer 1, one step behind, same j's.
// NO __syncthreads in the loop: each group stages its tagged-poll results in
// private LDS and syncs its 4 waves with an LDS-atomic barrier. Handoff is the
// round-1-proven tagged protocol (u32 = {tag,f16 h}) — detection IS data
// arrival, no extra read round-trip.
// L1 weights: Whh1 in VGPRs (128), Wih1 streamed from packed-f16 ws (off-chain).
__global__ __launch_bounds__(512, 1) void lstm_rec2(
    const float* __restrict__ Whh0,   // [8192][2048] layer 0
    const float* __restrict__ Whh1,   // [8192][2048] layer 1
    const unsigned* __restrict__ Wih1p, // [8192][1024] packed f16 pairs
    const unsigned* __restrict__ Gp,  // [T][4096] packed f16 pairs (x-contrib+bias)
    const float* __restrict__ bih1, const float* __restrict__ bhh1,
    const float* __restrict__ h0v,    // [2][2048]
    const float* __restrict__ c0v,    // [2][2048]
    unsigned* Hrow0, unsigned* Hrow1, // [T+1][2048] tagged u32
    float* __restrict__ hn, float* __restrict__ cn)
{
  const int b = blockIdx.x;
  const int tid = threadIdx.x;
  const int w = tid >> 6;
  const int lane = tid & 63;
  const bool isL0 = (w < 4);
  const int wq = isL0 ? w : (w - 4);
  const int j0 = b * 8 + 2 * wq;
  const int tg = wq * 64 + lane;        // 0..255 within the group

  __shared__ unsigned hsA[2][1024];     // L0: stripped h0 pairs
  __shared__ unsigned hsB0[2][1024];    // L1: stripped h0 pairs
  __shared__ unsigned hsB1[2][1024];    // L1: stripped h1 pairs
  __shared__ unsigned cntA, cntB;
  if (tid == 0) { cntA = 0u; cntB = 0u; }

  // Weight fragments: this wave's 2 rows x 4 gates of the recurrent matrix,
  // f16 pairs, 128 VGPRs. Lane's k-pairs: k = 256q + 4*lane + 2p, p in {0,1}.
  const float* Wsrc = isL0 ? Whh0 : Whh1;
  h2_t wr[2][4][16];
  #pragma unroll
  for (int jj = 0; jj < 2; ++jj)
    #pragma unroll
    for (int g = 0; g < 4; ++g) {
      const float* rp = Wsrc + (size_t)(g * 2048 + j0 + jj) * 2048;
      #pragma unroll
      for (int q = 0; q < 8; ++q)
        #pragma unroll
        for (int p = 0; p < 2; ++p) {
          float2 v = *(const float2*)(rp + 256 * q + 4 * lane + 2 * p);
          wr[jj][g][2 * q + p] = pk2(v.x, v.y);
        }
    }

  float bias_[2][4];
  if (!isL0) {
    #pragma unroll
    for (int jj = 0; jj < 2; ++jj)
      #pragma unroll
      for (int g = 0; g < 4; ++g)
        bias_[jj][g] = bih1[g * 2048 + j0 + jj] + bhh1[g * 2048 + j0 + jj];
  }

  const int lbase = isL0 ? 0 : HID;
  float cv[2], hv[2];
  cv[0] = c0v[lbase + j0];
  cv[1] = c0v[lbase + j0 + 1];
  hv[0] = 0.f; hv[1] = 0.f;

  // Publish row 0 (initial h) with tag 0.
  unsigned* Hmine = isL0 ? Hrow0 : Hrow1;
  if (lane < 2)
    st_sc4(Hmine + (j0 + lane), pkh(h0v[lbase + j0 + lane], 0u));
  __syncthreads();   // counters + init visible; the only WG-wide barrier

  if (isL0) {
    // ================= Layer 0: the critical chain =================
    for (int r = 1; r <= T_LEN; ++r) {
      // G prefetch (f16 pair holds both j0,j0+1); latency hides under the poll.
      unsigned gp = 0;
      if (lane < 4)
        gp = Gp[(size_t)(r - 1) * (G4 / 2) + lane * 1024 + (j0 >> 1)];
      // Tagged poll of row r-1: thread owns u32s [8tg, 8tg+8).
      const unsigned want = (unsigned)(r - 1);
      const unsigned* src = Hrow0 + (size_t)(r - 1) * 2048 + 8 * tg;
      uint4 u0, u1;
      int sp = 0;
      for (;;) {
        ld_sc16x2(src, src + 4, u0, u1);
        bool ok = ((u0.x >> 16) == want) & ((u0.y >> 16) == want) &
                  ((u0.z >> 16) == want) & ((u0.w >> 16) == want) &
                  ((u1.x >> 16) == want) & ((u1.y >> 16) == want) &
                  ((u1.z >> 16) == want) & ((u1.w >> 16) == want);
        if (ok) break;
        if (++sp > 6) __builtin_amdgcn_s_sleep(1);
        if (sp > (1 << 12)) break;   // valve: wrong, not hung
      }
      unsigned* dst = &hsA[r & 1][4 * tg];
      dst[0] = (u0.x & 0xffffu) | (u0.y << 16);
      dst[1] = (u0.z & 0xffffu) | (u0.w << 16);
      dst[2] = (u1.x & 0xffffu) | (u1.y << 16);
      dst[3] = (u1.z & 0xffffu) | (u1.w << 16);
      gbar(&cntA, 4u * (unsigned)r, lane);

      float a_[2][4] = {};
      #pragma unroll
      for (int q = 0; q < 8; ++q) {
        uint2 hp = *(const uint2*)&hsA[r & 1][128 * q + 2 * lane];
        h2_t h0p = bc2(hp.x), h1p = bc2(hp.y);
        #pragma unroll
        for (int jj = 0; jj < 2; ++jj)
          #pragma unroll
          for (int g = 0; g < 4; ++g) {
            a_[jj][g] = __builtin_amdgcn_fdot2(wr[jj][g][2*q],   h0p, a_[jj][g], false);
            a_[jj][g] = __builtin_amdgcn_fdot2(wr[jj][g][2*q+1], h1p, a_[jj][g], false);
          }
      }
      #pragma unroll
      for (int off = 32; off > 0; off >>= 1)
        #pragma unroll
        for (int jj = 0; jj < 2; ++jj)
          #pragma unroll
          for (int g = 0; g < 4; ++g)
            a_[jj][g] += __shfl_xor(a_[jj][g], off, 64);

      float gf[2][4];
      #pragma unroll
      for (int g = 0; g < 4; ++g) {
        unsigned gg_ = __shfl(gp, g, 64);
        gf[0][g] = uplo(gg_);
        gf[1][g] = uphi(gg_);
      }
      #pragma unroll
      for (int jj = 0; jj < 2; ++jj) {
        float ig = fsigmoid(a_[jj][0] + gf[jj][0]);
        float fg = fsigmoid(a_[jj][1] + gf[jj][1]);
        float gg = ftanh   (a_[jj][2] + gf[jj][2]);
        float og = fsigmoid(a_[jj][3] + gf[jj][3]);
        cv[jj] = fg * cv[jj] + ig * gg;
        hv[jj] = og * ftanh(cv[jj]);
      }
      if (lane < 2)
        st_sc4(Hrow0 + (size_t)r * 2048 + j0 + lane, pkh(hv[lane], (unsigned)r));
    }
    if (lane < 2) { hn[j0 + lane] = hv[lane]; cn[j0 + lane] = cv[lane]; }
  } else {
    // ================= Layer 1: off-chain, one step behind =================
    for (int s = 1; s <= T_LEN; ++s) {
      const unsigned want0 = (unsigned)s;         // h0 row s
      const unsigned want1 = (unsigned)(s - 1);   // h1 row s-1
      const unsigned* p0 = Hrow0 + (size_t)s * 2048 + 8 * tg;
      const unsigned* p1 = Hrow1 + (size_t)(s - 1) * 2048 + 8 * tg;
      uint4 a0, a1, b0, b1;
      int sp = 0;
      for (;;) {
        ld_sc16x4(p0, p0 + 4, p1, p1 + 4, a0, a1, b0, b1);
        bool ok = ((a0.x >> 16) == want0) & ((a0.y >> 16) == want0) &
                  ((a0.z >> 16) == want0) & ((a0.w >> 16) == want0) &
                  ((a1.x >> 16) == want0) & ((a1.y >> 16) == want0) &
                  ((a1.z >> 16) == want0) & ((a1.w >> 16) == want0) &
                  ((b0.x >> 16) == want1) & ((b0.y >> 16) == want1) &
                  ((b0.z >> 16) == want1) & ((b0.w >> 16) == want1) &
                  ((b1.x >> 16) == want1) & ((b1.y >> 16) == want1) &
                  ((b1.z >> 16) == want1) & ((b1.w >> 16) == want1);
        if (ok) break;
        if (++sp > 6) __builtin_amdgcn_s_sleep(1);
        if (sp > (1 << 12)) break;
      }
      unsigned* d0 = &hsB0[s & 1][4 * tg];
      d0[0] = (a0.x & 0xffffu) | (a0.y << 16);
      d0[1] = (a0.z & 0xffffu) | (a0.w << 16);
      d0[2] = (a1.x & 0xffffu) | (a1.y << 16);
      d0[3] = (a1.z & 0xffffu) | (a1.w << 16);
      unsigned* d1 = &hsB1[s & 1][4 * tg];
      d1[0] = (b0.x & 0xffffu) | (b0.y << 16);
      d1[1] = (b0.z & 0xffffu) | (b0.w << 16);
      d1[2] = (b1.x & 0xffffu) | (b1.y << 16);
      d1[3] = (b1.z & 0xffffu) | (b1.w << 16);
      gbar(&cntB, 4u * (unsigned)s, lane);

      float a_[2][4] = {};
      #pragma unroll
      for (int q = 0; q < 8; ++q) {
        uint2 xp = *(const uint2*)&hsB0[s & 1][128 * q + 2 * lane];
        uint2 yp = *(const uint2*)&hsB1[s & 1][128 * q + 2 * lane];
        h2_t x0 = bc2(xp.x), x1 = bc2(xp.y);
        h2_t y0 = bc2(yp.x), y1 = bc2(yp.y);
        #pragma unroll
        for (int jj = 0; jj < 2; ++jj)
          #pragma unroll
          for (int g = 0; g < 4; ++g) {
            uint2 wi = *(const uint2*)&Wih1p[(size_t)(g * 2048 + j0 + jj) * 1024
                                             + 128 * q + 2 * lane];
            a_[jj][g] = __builtin_amdgcn_fdot2(bc2(wi.x), x0, a_[jj][g], false);
            a_[jj][g] = __builtin_amdgcn_fdot2(bc2(wi.y), x1, a_[jj][g], false);
            a_[jj][g] = __builtin_amdgcn_fdot2(wr[jj][g][2*q],   y0, a_[jj][g], false);
            a_[jj][g] = __builtin_amdgcn_fdot2(wr[jj][g][2*q+1], y1, a_[jj][g], false);
          }
      }
      #pragma unroll
      for (int off = 32; off > 0; off >>= 1)
        #pragma unroll
        for (int jj = 0; jj < 2; ++jj)
          #pragma unroll
          for (int g = 0; g < 4; ++g)
            a_[jj][g] += __shfl_xor(a_[jj][g], off, 64);

      #pragma unroll
      for (int jj = 0; jj < 2; ++jj) {
        float ig = fsigmoid(a_[jj][0] + bias_[jj][0]);
        float fg = fsigmoid(a_[jj][1] + bias_[jj][1]);
        float gg = ftanh   (a_[jj][2] + bias_[jj][2]);
        float og = fsigmoid(a_[jj][3] + bias_[jj][3]);
        cv[jj] = fg * cv[jj] + ig * gg;
        hv[jj] = og * ftanh(cv[jj]);
      }
      if (lane < 2)
        st_sc4(Hrow1 + (size_t)s * 2048 + j0 + lane, pkh(hv[lane], (unsigned)s));
    }
    if (lane < 2) { hn[HID + j0 + lane] = hv[lane]; cn[HID + j0 + lane] = cv[lane]; }
  }
}

// ---------------- FC + log_softmax (tagged rows; strips lo16) ----------------
__global__ __launch_bounds__(128) void fc_lsm(
    const unsigned* __restrict__ Hrows,  // [T][2048] tagged (Hrow1 + 2048)
    const float* __restrict__ fcw,
    const float* __restrict__ fcb,
    float* __restrict__ out)
{
  const int t = blockIdx.x;
  const int v = threadIdx.x;
  __shared__ float hs[HID];
  __shared__ float red[4];
  const unsigned* hrow = Hrows + (size_t)t * HID;
  for (int q = v; q < HID / 4; q += 128) {
    uint4 uv = *(const uint4*)&hrow[q * 4];
    hs[q * 4 + 0] = uplo(uv.x); hs[q * 4 + 1] = uplo(uv.y);
    hs[q * 4 + 2] = uplo(uv.z); hs[q * 4 + 3] = uplo(uv.w);
  }
  __syncthreads();
  const float* wrow = fcw + (size_t)v * HID;
  float acc = fcb[v];
  #pragma unroll 4
  for (int k = 0; k < HID; k += 4) {
    float4 wv = *(const float4*)&wrow[k];
    acc = fmaf(wv.x, hs[k],     acc);
    acc = fmaf(wv.y, hs[k + 1], acc);
    acc = fmaf(wv.z, hs[k + 2], acc);
    acc = fmaf(wv.w, hs[k + 3], acc);
  }
  float m = acc;
  #pragma unroll
  for (int off = 32; off > 0; off >>= 1) m = fmaxf(m, __shfl_xor(m, off, 64));
  if ((v & 63) == 0) red[v >> 6] = m;
  __syncthreads();
  m = fmaxf(red[0], red[1]);
  float e = expf(acc - m), s = e;
  #pragma unroll
  for (int off = 32; off > 0; off >>= 1) s += __shfl_xor(s, off, 64);
  if ((v & 63) == 0) red[2 + (v >> 6)] = s;
  __syncthreads();
  s = red[2] + red[3];
  out[(size_t)t * NV + v] = (acc - m) - logf(s);
}

extern "C" void kernel_launch(void* const* d_in, const int* in_sizes, int n_in,
                              void* d_out, int out_size, void* d_ws, size_t ws_size,
                              hipStream_t stream) {
  const float* x   = (const float*)d_in[0];
  const float* h0  = (const float*)d_in[1];
  const float* c0  = (const float*)d_in[2];
  const float* Wih = (const float*)d_in[3];
  const float* Whh = (const float*)d_in[4];
  const float* bih = (const float*)d_in[5];
  const float* bhh = (const float*)d_in[6];
  const float* fcw = (const float*)d_in[7];
  const float* fcb = (const float*)d_in[8];
  float* out = (float*)d_out;

  // ws layout (bytes), total 100,679,680 (same as proven rounds):
  //   Gp     33,554,432   ([2048][4096] u32, packed f16 pairs)
  //   Hrow0  16,785,408   ([2049][2048] u32, tagged)
  //   Hrow1  16,785,408
  //   Wih1p  33,554,432   ([8192][1024] u32, packed f16 pairs)
  char* ws = (char*)d_ws;
  unsigned* Gp     = (unsigned*)(ws);
  unsigned* Hrow0  = (unsigned*)(ws + 33554432);
  unsigned* Hrow1  = (unsigned*)(ws + 33554432 + 16785408);
  unsigned* Wih1p  = (unsigned*)(ws + 33554432 + 2 * 16785408);

  dim3 ggrid(G4 / 64, T_LEN / 64);  // (128, 32)

  // Pre-pack layer-1 Wih to f16 pairs (off the critical path, ~50 µs).
  conv_pk<<<2048, 256, 0, stream>>>(Wih + (size_t)G4 * HID, Wih1p,
                                    (G4 * HID) / 4);
  // Layer-0 x-contribution GEMM, packed-f16 output with biases folded.
  gemm_bias_pk<<<ggrid, 256, 0, stream>>>(x, Wih, bih, bhh, Gp);
  // Fused wave-specialized 2-layer recurrence.
  lstm_rec2<<<256, 512, 0, stream>>>(Whh, Whh + (size_t)G4 * HID, Wih1p, Gp,
                                     bih + G4, bhh + G4, h0, c0,
                                     Hrow0, Hrow1,
                                     out + 262144, out + 266240);
  // FC + log_softmax on layer-1 rows 1..T.
  fc_lsm<<<T_LEN, 128, 0, stream>>>(Hrow1 + 2048, fcw, fcb, out);
}

// Round 6
// 13802.066 us; speedup vs baseline: 1.5605x; 1.5605x over previous
//
#include <hip/hip_runtime.h>
#include <hip/hip_fp16.h>

#define T_LEN 2048
#define HID   2048
#define G4    8192
#define NV    128

typedef _Float16 h2_t __attribute__((ext_vector_type(2)));
typedef unsigned short u16;

__device__ __forceinline__ float uplo(unsigned u) {
  return __half2float(__ushort_as_half((unsigned short)(u & 0xffffu)));
}
__device__ __forceinline__ float uphi(unsigned u) {
  return __half2float(__ushort_as_half((unsigned short)(u >> 16)));
}
__device__ __forceinline__ unsigned pku(float a, float b) {
  unsigned lo = (unsigned)__half_as_ushort(__float2half_rn(a));
  unsigned hi = (unsigned)__half_as_ushort(__float2half_rn(b));
  return lo | (hi << 16);
}
__device__ __forceinline__ h2_t pk2(float a, float bb) {
  return __builtin_bit_cast(h2_t, __builtin_amdgcn_cvt_pkrtz(a, bb));
}
__device__ __forceinline__ h2_t bc2(unsigned u) {
  return __builtin_bit_cast(h2_t, u);
}
// Zero-encoding: rows are write-once, so "ready" == "nonzero". The only f16
// colliding with the zero-init is +0.0 (0x0000) -> remap to the smallest
// subnormal (6e-8, far below f16 rounding noise).
__device__ __forceinline__ unsigned enc16(float h) {
  unsigned u = (unsigned)__half_as_ushort(__float2half_rn(h));
  return u ? u : 1u;
}

// Coherent (cache-bypassing) 16B load.
__device__ __forceinline__ uint4 ld_sc16(const unsigned* p) {
  uint4 r;
  asm volatile("global_load_dwordx4 %0, %1, off sc0 sc1\n\ts_waitcnt vmcnt(0)"
               : "=v"(r) : "v"(p) : "memory");
  return r;
}
// Coherent 2B store (fire-and-forget publish; low 16 bits of v).
__device__ __forceinline__ void st_sc2(u16* p, unsigned v) {
  asm volatile("global_store_short %0, %1, off sc0 sc1"
               :: "v"(p), "v"(v) : "memory");
}
// Coherent 16B store (zeroing kernel).
typedef unsigned u32x4 __attribute__((ext_vector_type(4)));
__device__ __forceinline__ void st_sc16(unsigned* p, u32x4 v) {
  asm volatile("global_store_dwordx4 %0, %1, off sc0 sc1"
               :: "v"(p), "v"(v) : "memory");
}

__device__ __forceinline__ float fsigmoid(float x) {
  return __builtin_amdgcn_rcpf(1.f + __expf(-x));
}
__device__ __forceinline__ float ftanh(float x) {
  return 2.f * __builtin_amdgcn_rcpf(1.f + __expf(-2.f * x)) - 1.f;
}

// Zero the Hrow arrays with coherent stores (visible to bypassing poll loads).
__global__ __launch_bounds__(256) void zero_rows(unsigned* f, int n4) {
  u32x4 z = {0u, 0u, 0u, 0u};
  for (int i = blockIdx.x * 256 + threadIdx.x; i < n4; i += gridDim.x * 256)
    st_sc16(f + 4 * (size_t)i, z);
}

// ---------------- GEMM: Gp (packed f16 pairs) = A@B^T + (b1+b2) ----------------
__global__ __launch_bounds__(256, 2) void gemm_bias_pk(
    const float* __restrict__ A, const float* __restrict__ B,
    const float* __restrict__ b1, const float* __restrict__ b2,
    unsigned* __restrict__ Gp)
{
  const int K = 2048;
  __shared__ float As[32][68];
  __shared__ float Bs[32][68];
  const int tid = threadIdx.x;
  const int tx = tid & 15, ty = tid >> 4;
  const int row0 = blockIdx.y * 64, col0 = blockIdx.x * 64;
  const int lk = (tid & 7) * 4, lr = tid >> 3;
  float acc[4][4] = {};
  for (int k0 = 0; k0 < K; k0 += 32) {
    float4 a0 = *(const float4*)&A[(size_t)(row0 + lr)      * K + k0 + lk];
    float4 a1 = *(const float4*)&A[(size_t)(row0 + lr + 32) * K + k0 + lk];
    float4 bb0 = *(const float4*)&B[(size_t)(col0 + lr)      * K + k0 + lk];
    float4 bb1 = *(const float4*)&B[(size_t)(col0 + lr + 32) * K + k0 + lk];
    __syncthreads();
    As[lk+0][lr] = a0.x;  As[lk+1][lr] = a0.y;  As[lk+2][lr] = a0.z;  As[lk+3][lr] = a0.w;
    As[lk+0][lr+32] = a1.x; As[lk+1][lr+32] = a1.y; As[lk+2][lr+32] = a1.z; As[lk+3][lr+32] = a1.w;
    Bs[lk+0][lr] = bb0.x; Bs[lk+1][lr] = bb0.y; Bs[lk+2][lr] = bb0.z; Bs[lk+3][lr] = bb0.w;
    Bs[lk+0][lr+32] = bb1.x; Bs[lk+1][lr+32] = bb1.y; Bs[lk+2][lr+32] = bb1.z; Bs[lk+3][lr+32] = bb1.w;
    __syncthreads();
    #pragma unroll
    for (int kk = 0; kk < 32; ++kk) {
      float4 av = *(const float4*)&As[kk][ty * 4];
      float4 bv = *(const float4*)&Bs[kk][tx * 4];
      float am[4] = {av.x, av.y, av.z, av.w};
      float bm[4] = {bv.x, bv.y, bv.z, bv.w};
      #pragma unroll
      for (int i = 0; i < 4; ++i)
        #pragma unroll
        for (int j = 0; j < 4; ++j)
          acc[i][j] = fmaf(am[i], bm[j], acc[i][j]);
    }
  }
  const int cc = col0 + tx * 4;
  const float bbv0 = b1[cc+0] + b2[cc+0];
  const float bbv1 = b1[cc+1] + b2[cc+1];
  const float bbv2 = b1[cc+2] + b2[cc+2];
  const float bbv3 = b1[cc+3] + b2[cc+3];
  #pragma unroll
  for (int i = 0; i < 4; ++i) {
    const int r = row0 + ty * 4 + i;
    unsigned* gp = Gp + (size_t)r * (G4 / 2) + (cc >> 1);
    gp[0] = pku(acc[i][0] + bbv0, acc[i][1] + bbv1);
    gp[1] = pku(acc[i][2] + bbv2, acc[i][3] + bbv3);
  }
}

// ---------------- Fused 2-layer persistent recurrent kernel ----------------
// Round-1-proven structure: 256 WGs x 512 threads, 1 WG/CU; wave w owns
// j = 8b+w for both layers; pipeline skew 1 (iter r = L0 step r + L1 step r-1);
// one __syncthreads per iteration; L1 compute hidden after the L0 publish.
//
// Protocol v2 (zero-encoding): rows are untagged u16 f16 (4KB, half of
// tagged). Readiness = value nonzero (rows zeroed at launch; +0 remapped to
// subnormal). Probe split: waves 0-3 poll the h0 row, waves 4-7 poll the h1
// row -> 512x16B txns/WG/round, HALF of round-1's dual-poll flood. Publishes
// are 2B stores. Detection is still data arrival: no extra RTT anywhere.
__global__ __launch_bounds__(512, 2) void lstm_rec2(
    const float* __restrict__ Whh0,  // [8192][2048] layer 0
    const float* __restrict__ Wih1,  // [8192][2048] layer 1
    const float* __restrict__ Whh1,  // [8192][2048] layer 1
    const unsigned* __restrict__ Gp, // [T][4096] packed f16 pairs (x + biases)
    const float* __restrict__ bih1, const float* __restrict__ bhh1,
    const float* __restrict__ h0v,   // [2][2048]
    const float* __restrict__ c0v,   // [2][2048]
    u16* Hrow0, u16* Hrow1,          // [T+1][2048] f16 (zero-enc)
    float* __restrict__ hn, float* __restrict__ cn)
{
  const int b = blockIdx.x;
  const int tid = threadIdx.x;
  const int w = tid >> 6;
  const int lane = tid & 63;
  const int j = b * 8 + w;
  __shared__ unsigned hs0[2][HID / 2];
  __shared__ unsigned hs1[2][HID / 2];

  // Weight fragments (f16 pairs), 3 x 64 regs, loaded once.
  h2_t wreg0[4][16], wregI[4][16], wregH[4][16];
  #pragma unroll
  for (int g = 0; g < 4; ++g) {
    const float* r0 = Whh0 + (size_t)(g * 2048 + j) * 2048 + 2 * lane;
    #pragma unroll
    for (int it = 0; it < 16; ++it) {
      float2 v = *(const float2*)(r0 + 128 * it);
      wreg0[g][it] = pk2(v.x, v.y);
    }
  }
  #pragma unroll
  for (int g = 0; g < 4; ++g) {
    const float* rI = Wih1 + (size_t)(g * 2048 + j) * 2048 + 2 * lane;
    #pragma unroll
    for (int it = 0; it < 16; ++it) {
      float2 v = *(const float2*)(rI + 128 * it);
      wregI[g][it] = pk2(v.x, v.y);
    }
  }
  #pragma unroll
  for (int g = 0; g < 4; ++g) {
    const float* rH = Whh1 + (size_t)(g * 2048 + j) * 2048 + 2 * lane;
    #pragma unroll
    for (int it = 0; it < 16; ++it) {
      float2 v = *(const float2*)(rH + 128 * it);
      wregH[g][it] = pk2(v.x, v.y);
    }
  }
  float bias1[4];
  #pragma unroll
  for (int g = 0; g < 4; ++g)
    bias1[g] = bih1[g * 2048 + j] + bhh1[g * 2048 + j];

  float c0val = c0v[j];
  float c1val = c0v[HID + j];
  float h0last = 0.f, h1last = 0.f;

  // Publish row 0 (initial h, all-zero in this problem -> enc to subnormal).
  if (lane == 0) {
    st_sc2(Hrow0 + j, enc16(h0v[j]));
    st_sc2(Hrow1 + j, enc16(h0v[HID + j]));
  }

  const unsigned* H0_32 = (const unsigned*)Hrow0;
  const unsigned* H1_32 = (const unsigned*)Hrow1;

  for (int r = 1; r <= T_LEN + 1; ++r) {
    const bool doL0 = (r <= T_LEN);
    const bool doL1 = (r >= 2);
    // Prefetch this step's G (packed pair holds j and j^1; pick half later).
    unsigned gpre = 0;
    if (doL0 && lane < 4)
      gpre = Gp[(size_t)(r - 1) * (G4 / 2) + lane * 1024 + (j >> 1)];

    // Poll split: waves 0-3 own the h0 row r-1 (16B = 8 values each thread);
    // waves 4-7 own the h1 row r-2 (older; usually first-probe hit).
    if (tid < 256) {
      const unsigned* src = H0_32 + (size_t)(r - 1) * 1024 + 4 * tid;
      uint4 u;
      int sp = 0;
      for (;;) {
        u = ld_sc16(src);
        bool ok = (u.x & 0xffffu) && (u.x >> 16) && (u.y & 0xffffu) && (u.y >> 16) &&
                  (u.z & 0xffffu) && (u.z >> 16) && (u.w & 0xffffu) && (u.w >> 16);
        if (ok) break;
        if (++sp > 4) __builtin_amdgcn_s_sleep(1);
        if (sp > (1 << 15)) break;   // valve: wrong, not hung
      }
      unsigned* d = &hs0[r & 1][4 * tid];
      d[0] = u.x; d[1] = u.y; d[2] = u.z; d[3] = u.w;
    } else if (doL1) {
      const int q = tid - 256;
      const unsigned* src = H1_32 + (size_t)(r - 2) * 1024 + 4 * q;
      uint4 u;
      int sp = 0;
      for (;;) {
        u = ld_sc16(src);
        bool ok = (u.x & 0xffffu) && (u.x >> 16) && (u.y & 0xffffu) && (u.y >> 16) &&
                  (u.z & 0xffffu) && (u.z >> 16) && (u.w & 0xffffu) && (u.w >> 16);
        if (ok) break;
        if (++sp > 4) __builtin_amdgcn_s_sleep(1);
        if (sp > (1 << 15)) break;
      }
      unsigned* d = &hs1[r & 1][4 * q];
      d[0] = u.x; d[1] = u.y; d[2] = u.z; d[3] = u.w;
    }
    __syncthreads();

    // ---- Layer 0 step r (critical chain) ----
    if (doL0) {
      const unsigned* hr = hs0[r & 1];
      float a0 = 0.f, a1 = 0.f, a2 = 0.f, a3 = 0.f;
      #pragma unroll
      for (int it = 0; it < 16; ++it) {
        h2_t hv = bc2(hr[lane + 64 * it]);
        a0 = __builtin_amdgcn_fdot2(wreg0[0][it], hv, a0, false);
        a1 = __builtin_amdgcn_fdot2(wreg0[1][it], hv, a1, false);
        a2 = __builtin_amdgcn_fdot2(wreg0[2][it], hv, a2, false);
        a3 = __builtin_amdgcn_fdot2(wreg0[3][it], hv, a3, false);
      }
      #pragma unroll
      for (int off = 32; off > 0; off >>= 1) {
        a0 += __shfl_xor(a0, off, 64);
        a1 += __shfl_xor(a1, off, 64);
        a2 += __shfl_xor(a2, off, 64);
        a3 += __shfl_xor(a3, off, 64);
      }
      unsigned gu0 = __shfl(gpre, 0, 64), gu1 = __shfl(gpre, 1, 64);
      unsigned gu2 = __shfl(gpre, 2, 64), gu3 = __shfl(gpre, 3, 64);
      const bool hi = (j & 1);
      float g0 = hi ? uphi(gu0) : uplo(gu0);
      float g1 = hi ? uphi(gu1) : uplo(gu1);
      float g2 = hi ? uphi(gu2) : uplo(gu2);
      float g3 = hi ? uphi(gu3) : uplo(gu3);
      float ig = fsigmoid(a0 + g0);
      float fg = fsigmoid(a1 + g1);
      float gg = ftanh(a2 + g2);
      float og = fsigmoid(a3 + g3);
      c0val = fg * c0val + ig * gg;
      h0last = og * ftanh(c0val);
      if (lane == 0)
        st_sc2(Hrow0 + (size_t)r * HID + j, enc16(h0last));
    }

    // ---- Layer 1 step r-1 (off the chain; x = hs0 from this iter) ----
    if (doL1) {
      const unsigned* xr = hs0[r & 1];
      const unsigned* hr = hs1[r & 1];
      float a0 = 0.f, a1 = 0.f, a2 = 0.f, a3 = 0.f;
      #pragma unroll
      for (int it = 0; it < 16; ++it) {
        h2_t xv = bc2(xr[lane + 64 * it]);
        a0 = __builtin_amdgcn_fdot2(wregI[0][it], xv, a0, false);
        a1 = __builtin_amdgcn_fdot2(wregI[1][it], xv, a1, false);
        a2 = __builtin_amdgcn_fdot2(wregI[2][it], xv, a2, false);
        a3 = __builtin_amdgcn_fdot2(wregI[3][it], xv, a3, false);
        h2_t hv = bc2(hr[lane + 64 * it]);
        a0 = __builtin_amdgcn_fdot2(wregH[0][it], hv, a0, false);
        a1 = __builtin_amdgcn_fdot2(wregH[1][it], hv, a1, false);
        a2 = __builtin_amdgcn_fdot2(wregH[2][it], hv, a2, false);
        a3 = __builtin_amdgcn_fdot2(wregH[3][it], hv, a3, false);
      }
      #pragma unroll
      for (int off = 32; off > 0; off >>= 1) {
        a0 += __shfl_xor(a0, off, 64);
        a1 += __shfl_xor(a1, off, 64);
        a2 += __shfl_xor(a2, off, 64);
        a3 += __shfl_xor(a3, off, 64);
      }
      float ig = fsigmoid(a0 + bias1[0]);
      float fg = fsigmoid(a1 + bias1[1]);
      float gg = ftanh(a2 + bias1[2]);
      float og = fsigmoid(a3 + bias1[3]);
      c1val = fg * c1val + ig * gg;
      h1last = og * ftanh(c1val);
      if (lane == 0)
        st_sc2(Hrow1 + (size_t)(r - 1) * HID + j, enc16(h1last));
    }
    // No end-of-step barrier: double-buffered hs + one barrier/step.
  }
  if (lane == 0) {
    hn[j] = h0last;       cn[j] = c0val;
    hn[HID + j] = h1last; cn[HID + j] = c1val;
  }
}

// ---------------- FC + log_softmax (u16 f16 rows) ----------------
__global__ __launch_bounds__(128) void fc_lsm(
    const u16* __restrict__ Hrows,   // [T][2048] f16 (Hrow1 + 2048)
    const float* __restrict__ fcw,   // [128][2048]
    const float* __restrict__ fcb,   // [128]
    float* __restrict__ out)         // [T][128]
{
  const int t = blockIdx.x;
  const int v = threadIdx.x;
  __shared__ float hs[HID];
  __shared__ float red[4];
  const unsigned* hrow = (const unsigned*)(Hrows + (size_t)t * HID);
  for (int q = v; q < 256; q += 128) {
    uint4 uv = *(const uint4*)&hrow[q * 4];
    hs[q*8+0] = uplo(uv.x); hs[q*8+1] = uphi(uv.x);
    hs[q*8+2] = uplo(uv.y); hs[q*8+3] = uphi(uv.y);
    hs[q*8+4] = uplo(uv.z); hs[q*8+5] = uphi(uv.z);
    hs[q*8+6] = uplo(uv.w); hs[q*8+7] = uphi(uv.w);
  }
  __syncthreads();
  const float* wrow = fcw + (size_t)v * HID;
  float acc = fcb[v];
  #pragma unroll 4
  for (int k = 0; k < HID; k += 4) {
    float4 wv = *(const float4*)&wrow[k];
    acc = fmaf(wv.x, hs[k],     acc);
    acc = fmaf(wv.y, hs[k + 1], acc);
    acc = fmaf(wv.z, hs[k + 2], acc);
    acc = fmaf(wv.w, hs[k + 3], acc);
  }
  float m = acc;
  #pragma unroll
  for (int off = 32; off > 0; off >>= 1) m = fmaxf(m, __shfl_xor(m, off, 64));
  if ((v & 63) == 0) red[v >> 6] = m;
  __syncthreads();
  m = fmaxf(red[0], red[1]);
  float e = expf(acc - m), s = e;
  #pragma unroll
  for (int off = 32; off > 0; off >>= 1) s += __shfl_xor(s, off, 64);
  if ((v & 63) == 0) red[2 + (v >> 6)] = s;
  __syncthreads();
  s = red[2] + red[3];
  out[(size_t)t * NV + v] = (acc - m) - logf(s);
}

extern "C" void kernel_launch(void* const* d_in, const int* in_sizes, int n_in,
                              void* d_out, int out_size, void* d_ws, size_t ws_size,
                              hipStream_t stream) {
  const float* x   = (const float*)d_in[0];
  const float* h0  = (const float*)d_in[1];
  const float* c0  = (const float*)d_in[2];
  const float* Wih = (const float*)d_in[3];
  const float* Whh = (const float*)d_in[4];
  const float* bih = (const float*)d_in[5];
  const float* bhh = (const float*)d_in[6];
  const float* fcw = (const float*)d_in[7];
  const float* fcb = (const float*)d_in[8];
  float* out = (float*)d_out;

  // ws layout (bytes):
  //   Gp     33,554,432   ([2048][4096] u32, packed f16 pairs, biases folded)
  //   Hrow0   8,392,704   ([2049][2048] u16, zero-enc f16)
  //   Hrow1   8,392,704
  char* ws = (char*)d_ws;
  unsigned* Gp    = (unsigned*)(ws);
  u16*      Hrow0 = (u16*)(ws + 33554432);
  u16*      Hrow1 = (u16*)(ws + 33554432 + 8392704);

  // Rows must start zero each launch/replay (nonzero == ready).
  const int nrow4 = (2 * 8392704) / 16;
  zero_rows<<<512, 256, 0, stream>>>((unsigned*)Hrow0, nrow4);

  dim3 ggrid(G4 / 64, T_LEN / 64);  // (128, 32)

  // Layer-0 x-contribution GEMM (packed f16 output, biases folded).
  gemm_bias_pk<<<ggrid, 256, 0, stream>>>(x, Wih, bih, bhh, Gp);
  // Fused 2-layer pipelined recurrence (round-1 structure, slim protocol).
  lstm_rec2<<<256, 512, 0, stream>>>(Whh, Wih + (size_t)G4 * HID,
                                     Whh + (size_t)G4 * HID, Gp,
                                     bih + G4, bhh + G4, h0, c0,
                                     Hrow0, Hrow1,
                                     out + 262144, out + 266240);
  // FC + log_softmax on layer-1 rows 1..T.
  fc_lsm<<<T_LEN, 128, 0, stream>>>(Hrow1 + HID, fcw, fcb, out);
}